// Round 11
// baseline (1331.851 us; speedup 1.0000x reference)
//
#include <hip/hip_runtime.h>

constexpr int C_DIM = 256;

using f32x4  = __attribute__((ext_vector_type(4))) float;
using bf16x8 = __attribute__((ext_vector_type(8))) short;

__device__ __forceinline__ float uf(uint u) { return __uint_as_float(u); }
__device__ __forceinline__ uint  fu(float f) { return __float_as_uint(f); }

typedef __attribute__((address_space(3))) unsigned int lds_u32;
typedef const __attribute__((address_space(1))) unsigned int glb_u32;

// HBM -> LDS direct DMA, 16B per lane. lds dest = uniform base + lane*16.
__device__ __forceinline__ void gll16(const ushort* g, ushort* l) {
    __builtin_amdgcn_global_load_lds((glb_u32*)g, (lds_u32*)l, 16, 0, 0);
}

// ---------------- CSR build ----------------

__global__ void k_zero_i32(int* __restrict__ p, int n) {
    int i = blockIdx.x * blockDim.x + threadIdx.x;
    if (i < n) p[i] = 0;
}

__global__ void k_hist(const int* __restrict__ dst, int E, int* __restrict__ cnt) {
    int e = blockIdx.x * blockDim.x + threadIdx.x;
    if (e < E) atomicAdd(&cnt[dst[e]], 1);
}

__global__ __launch_bounds__(1024) void k_scan(const int* __restrict__ cnt,
                                               int* __restrict__ off, int n) {
    __shared__ int sh[1024];
    const int tid = threadIdx.x;
    const int chunk = (n + 1023) >> 10;
    const int s = tid * chunk;
    const int e = min(s + chunk, n);
    int sum = 0;
    for (int i = s; i < e; i++) sum += cnt[i];
    sh[tid] = sum;
    __syncthreads();
    for (int ofs = 1; ofs < 1024; ofs <<= 1) {
        int t = (tid >= ofs) ? sh[tid - ofs] : 0;
        __syncthreads();
        sh[tid] += t;
        __syncthreads();
    }
    int run = sh[tid] - sum;
    for (int i = s; i < e; i++) { off[i] = run; run += cnt[i]; }
    if (tid == 1023) off[n] = sh[1023];
}

__global__ void k_copy_i32(const int* __restrict__ a, int* __restrict__ b, int n) {
    int i = blockIdx.x * blockDim.x + threadIdx.x;
    if (i < n) b[i] = a[i];
}

__global__ void k_scatter(const int* __restrict__ src, const int* __restrict__ dst, int E,
                          int* __restrict__ cur, int* __restrict__ adj) {
    int e = blockIdx.x * blockDim.x + threadIdx.x;
    if (e < E) {
        int p = atomicAdd(&cur[dst[e]], 1);
        adj[p] = src[e];
    }
}

// ---------------- H = x + A*x, split-plane I/O ----------------
template <int SPLIT_IN>
__global__ __launch_bounds__(256) void k_agg2(const float* __restrict__ xf,
        const ushort* __restrict__ xh, const ushort* __restrict__ xl,
        const int* __restrict__ off, const int* __restrict__ adj,
        ushort* __restrict__ Hh, ushort* __restrict__ Hl, int n) {
    const int node = blockIdx.x * 4 + (threadIdx.x >> 6);
    if (node >= n) return;
    const int lane = threadIdx.x & 63;
    float a0, a1, a2, a3;
    if (SPLIT_IN) {
        const uint2 h  = ((const uint2*)(xh + (size_t)node * C_DIM))[lane];
        const uint2 lo = ((const uint2*)(xl + (size_t)node * C_DIM))[lane];
        a0 = uf(h.x << 16) + uf(lo.x << 16);
        a1 = uf(h.x & 0xffff0000u) + uf(lo.x & 0xffff0000u);
        a2 = uf(h.y << 16) + uf(lo.y << 16);
        a3 = uf(h.y & 0xffff0000u) + uf(lo.y & 0xffff0000u);
    } else {
        const float4 v = ((const float4*)(xf + (size_t)node * C_DIM))[lane];
        a0 = v.x; a1 = v.y; a2 = v.z; a3 = v.w;
    }
    const int s = off[node], e = off[node + 1];
    for (int j = s; j < e; j++) {
        const int sn = adj[j];
        if (SPLIT_IN) {
            const uint2 h  = ((const uint2*)(xh + (size_t)sn * C_DIM))[lane];
            const uint2 lo = ((const uint2*)(xl + (size_t)sn * C_DIM))[lane];
            a0 += uf(h.x << 16) + uf(lo.x << 16);
            a1 += uf(h.x & 0xffff0000u) + uf(lo.x & 0xffff0000u);
            a2 += uf(h.y << 16) + uf(lo.y << 16);
            a3 += uf(h.y & 0xffff0000u) + uf(lo.y & 0xffff0000u);
        } else {
            const float4 v = ((const float4*)(xf + (size_t)sn * C_DIM))[lane];
            a0 += v.x; a1 += v.y; a2 += v.z; a3 += v.w;
        }
    }
    const uint u0 = fu(a0), u1 = fu(a1), u2 = fu(a2), u3 = fu(a3);
    uint2 ho, lo_;
    ho.x = (u0 >> 16) | (u1 & 0xffff0000u);
    ho.y = (u2 >> 16) | (u3 & 0xffff0000u);
    const float r0 = a0 - uf(u0 & 0xffff0000u);
    const float r1 = a1 - uf(u1 & 0xffff0000u);
    const float r2 = a2 - uf(u2 & 0xffff0000u);
    const float r3 = a3 - uf(u3 & 0xffff0000u);
    lo_.x = (fu(r0) >> 16) | (fu(r1) & 0xffff0000u);
    lo_.y = (fu(r2) >> 16) | (fu(r3) & 0xffff0000u);
    ((uint2*)(Hh + (size_t)node * C_DIM))[lane] = ho;
    ((uint2*)(Hl + (size_t)node * C_DIM))[lane] = lo_;
}

// ---------------- weight split + transpose ----------------
__global__ void k_split_w(const float* __restrict__ W, ushort* __restrict__ hi,
                          ushort* __restrict__ lo, int K, int M, int total) {
    int i = blockIdx.x * blockDim.x + threadIdx.x;
    if (i >= total) return;
    const int KM = K * M;
    const int mi = i / KM, rem = i - mi * KM;
    const int k = rem / M, m = rem - k * M;
    const float x = W[i];
    const uint u = fu(x);
    const float lf = x - uf(u & 0xffff0000u);
    const int oidx = mi * KM + m * K + k;
    hi[oidx] = (ushort)(u >> 16);
    lo[oidx] = (ushort)(fu(lf) >> 16);
}

// ---------------- Y = act(X @ W + b), pre-split bf16 MFMA, full-width tile ----
// A planes: [n][K] bf16 hi/lo. B planes: [M][K] bf16 hi/lo.
// BM=64, BN=M (full width): each block computes COMPLETE output rows -> A read
// exactly once per GEMM (no inter-block A sharing; no XCD swizzle needed).
// 4 waves in 2x2; wave owns 32 rows x BN/2 cols. LDS linear 64B rows + 16B-slot
// XOR swizzle (pre-swizzled global src + swizzled read) for conflict-free frags.
template <int RELU, int OSPLIT, int BN>
__global__ __launch_bounds__(256) void k_gemm7(const ushort* __restrict__ Ah,
        const ushort* __restrict__ Al, const ushort* __restrict__ Bh,
        const ushort* __restrict__ Bl, const float* __restrict__ bias,
        float* __restrict__ Yf, ushort* __restrict__ Yh, ushort* __restrict__ Yl,
        int n, int K) {
    constexpr int NBC = BN / 16;        // B col-chunks per plane
    constexpr int NCHUNK = 8 + 2 * NBC; // A chunks (8) + B chunks
    constexpr int NF = BN / 32;         // col-frags per wave
    __shared__ ushort AsH[64 * 32], AsL[64 * 32], BsH[BN * 32], BsL[BN * 32];

    const int tid = threadIdx.x;
    const int l = tid & 63, w = tid >> 6;
    const int wr = w >> 1, wc = w & 1;
    const int lr = l & 15, lkq = l >> 4;
    const int row0 = blockIdx.x * 64;
    f32x4 acc[2][NF] = {};

    const int lsub = l >> 2;                               // row within 16-row chunk
    const int lkb  = (((l & 3) ^ ((l >> 3) & 3)) * 8);     // inverse-swizzled k-slot
    const int swz  = (lkq ^ ((lr >> 1) & 3)) * 8;          // read-side swizzle

    for (int k0 = 0; k0 < K; k0 += 32) {
        __syncthreads();   // previous iteration's LDS reads complete
        // 1KB chunks: A rows (4/plane), B cols (NBC/plane); uniform branches
        for (int c = w; c < NCHUNK; c += 4) {
            if (c < 8) {
                const int a = c & 3;
                const int grow = min(row0 + a * 16 + lsub, n - 1);
                const ushort* gp = (c < 4 ? Ah : Al) + (size_t)grow * K + k0 + lkb;
                ushort* lp = (c < 4 ? AsH : AsL) + a * 512;
                gll16(gp, lp);
            } else {
                const int bc = c - 8;
                const int cc = bc & (NBC - 1);
                const int col = cc * 16 + lsub;
                const ushort* gp = (bc < NBC ? Bh : Bl) + (size_t)col * K + k0 + lkb;
                ushort* lp = (bc < NBC ? BsH : BsL) + cc * 512;
                gll16(gp, lp);
            }
        }
        __syncthreads();   // vmcnt(0) drained before barrier: tile ready

        bf16x8 aH[2], aL[2];
#pragma unroll
        for (int fi = 0; fi < 2; fi++) {
            const int rr = (wr * 32 + fi * 16 + lr) * 32 + swz;
            aH[fi] = *(const bf16x8*)&AsH[rr];
            aL[fi] = *(const bf16x8*)&AsL[rr];
        }
#pragma unroll
        for (int fj = 0; fj < NF; fj++) {
            const int rr = (wc * (BN / 2) + fj * 16 + lr) * 32 + swz;
            const bf16x8 bH = *(const bf16x8*)&BsH[rr];
            const bf16x8 bL = *(const bf16x8*)&BsL[rr];
#pragma unroll
            for (int fi = 0; fi < 2; fi++) {
                acc[fi][fj] = __builtin_amdgcn_mfma_f32_16x16x32_bf16(aH[fi], bH, acc[fi][fj], 0, 0, 0);
                acc[fi][fj] = __builtin_amdgcn_mfma_f32_16x16x32_bf16(aL[fi], bH, acc[fi][fj], 0, 0, 0);
                acc[fi][fj] = __builtin_amdgcn_mfma_f32_16x16x32_bf16(aH[fi], bL, acc[fi][fj], 0, 0, 0);
            }
        }
    }

    // C/D layout: col = lane&15, row = (lane>>4)*4 + reg
#pragma unroll
    for (int fi = 0; fi < 2; fi++)
#pragma unroll
        for (int fj = 0; fj < NF; fj++) {
            const int col = wc * (BN / 2) + fj * 16 + lr;
            const float bv = bias[col];
#pragma unroll
            for (int rg = 0; rg < 4; rg++) {
                const int row = row0 + wr * 32 + fi * 16 + lkq * 4 + rg;
                if (row < n) {
                    float v = acc[fi][fj][rg] + bv;
                    if (RELU) v = fmaxf(v, 0.f);
                    const size_t oi = (size_t)row * BN + col;
                    if (OSPLIT) {
                        const uint u = fu(v);
                        const float rv = v - uf(u & 0xffff0000u);
                        Yh[oi] = (ushort)(u >> 16);
                        Yl[oi] = (ushort)(fu(rv) >> 16);
                    } else {
                        Yf[oi] = v;
                    }
                }
            }
        }
}

// ---------------- driver ----------------

extern "C" void kernel_launch(void* const* d_in, const int* in_sizes, int n_in,
                              void* d_out, int out_size, void* d_ws, size_t ws_size,
                              hipStream_t stream) {
    const float* x   = (const float*)d_in[0];
    const int*   src = (const int*)d_in[1];
    const int*   dst = (const int*)d_in[2];
    const float* W1s = (const float*)d_in[3];
    const float* b1s = (const float*)d_in[4];
    const float* W2s = (const float*)d_in[5];
    const float* b2s = (const float*)d_in[6];
    const float* W3s = (const float*)d_in[7];
    const float* b3s = (const float*)d_in[8];
    const float* cW1 = (const float*)d_in[9];
    const float* cb1 = (const float*)d_in[10];
    const float* cW2 = (const float*)d_in[11];
    const float* cb2 = (const float*)d_in[12];
    const float* cW3 = (const float*)d_in[13];
    const float* cb3 = (const float*)d_in[14];

    const int n  = in_sizes[0] / C_DIM;                 // 50000
    const int E  = in_sizes[1];                         // 800000
    const int NL = in_sizes[3] / (C_DIM * C_DIM);       // 3 inner layers

    char* wsp = (char*)d_ws;
    size_t o = 0;
    auto take = [&](size_t bytes) -> char* {
        char* p = wsp + o;
        o = (o + bytes + 255) & ~(size_t)255;
        return p;
    };
    int* off = (int*)take(sizeof(int) * (size_t)(n + 1));
    int* cur = (int*)take(sizeof(int) * (size_t)n);
    int* adj = (int*)take(sizeof(int) * (size_t)E);
    const size_t plane = (size_t)n * C_DIM;
    ushort* B0h = (ushort*)take(2 * plane);
    ushort* B0l = (ushort*)take(2 * plane);
    ushort* B1h = (ushort*)take(2 * plane);
    ushort* B1l = (ushort*)take(2 * plane);
    // d_out doubles as the B2 ping-pong pair (dead before the final fp32 write)
    ushort* B2h = (ushort*)d_out;
    ushort* B2l = B2h + plane;

    const int szW  = NL * C_DIM * C_DIM;
    const int szC1 = C_DIM * C_DIM;
    const int szC2 = C_DIM * 64;
    const int szC3 = 64 * C_DIM;
    ushort* W1tH = (ushort*)take(2ull * szW);
    ushort* W1tL = (ushort*)take(2ull * szW);
    ushort* W2tH = (ushort*)take(2ull * szW);
    ushort* W2tL = (ushort*)take(2ull * szW);
    ushort* W3tH = (ushort*)take(2ull * szW);
    ushort* W3tL = (ushort*)take(2ull * szW);
    ushort* C1tH = (ushort*)take(2ull * szC1);
    ushort* C1tL = (ushort*)take(2ull * szC1);
    ushort* C2tH = (ushort*)take(2ull * szC2);
    ushort* C2tL = (ushort*)take(2ull * szC2);
    ushort* C3tH = (ushort*)take(2ull * szC3);
    ushort* C3tL = (ushort*)take(2ull * szC3);
    float* out = (float*)d_out;

    const dim3 b256(256);

    // weight preprocessing (split + transpose)
    k_split_w<<<dim3((szW + 255) / 256), b256, 0, stream>>>(W1s, W1tH, W1tL, C_DIM, C_DIM, szW);
    k_split_w<<<dim3((szW + 255) / 256), b256, 0, stream>>>(W2s, W2tH, W2tL, C_DIM, C_DIM, szW);
    k_split_w<<<dim3((szW + 255) / 256), b256, 0, stream>>>(W3s, W3tH, W3tL, C_DIM, C_DIM, szW);
    k_split_w<<<dim3((szC1 + 255) / 256), b256, 0, stream>>>(cW1, C1tH, C1tL, C_DIM, C_DIM, szC1);
    k_split_w<<<dim3((szC2 + 255) / 256), b256, 0, stream>>>(cW2, C2tH, C2tL, C_DIM, 64, szC2);
    k_split_w<<<dim3((szC3 + 255) / 256), b256, 0, stream>>>(cW3, C3tH, C3tL, 64, C_DIM, szC3);

    // CSR build
    k_zero_i32<<<dim3((n + 255) / 256), b256, 0, stream>>>(cur, n);
    k_hist<<<dim3((E + 255) / 256), b256, 0, stream>>>(dst, E, cur);
    k_scan<<<1, 1024, 0, stream>>>(cur, off, n);
    k_copy_i32<<<dim3((n + 255) / 256), b256, 0, stream>>>(off, cur, n);
    k_scatter<<<dim3((E + 255) / 256), b256, 0, stream>>>(src, dst, E, cur, adj);

    const int gx = (n + 63) / 64;            // 782 row panels (full-width blocks)
    const dim3 gAgg((n + 3) / 4);

    // inner GIN layers: agg -> G1(relu) -> G2(relu) -> G3(linear)
    for (int lyr = 0; lyr < NL; lyr++) {
        const size_t wo = (size_t)lyr * C_DIM * C_DIM;
        if (lyr == 0)
            k_agg2<0><<<gAgg, b256, 0, stream>>>(x, nullptr, nullptr, off, adj, B1h, B1l, n);
        else
            k_agg2<1><<<gAgg, b256, 0, stream>>>(nullptr, B0h, B0l, off, adj, B1h, B1l, n);
        k_gemm7<1, 1, 256><<<dim3(gx), b256, 0, stream>>>(B1h, B1l, W1tH + wo, W1tL + wo,
            b1s + lyr * C_DIM, nullptr, B2h, B2l, n, C_DIM);
        k_gemm7<1, 1, 256><<<dim3(gx), b256, 0, stream>>>(B2h, B2l, W2tH + wo, W2tL + wo,
            b2s + lyr * C_DIM, nullptr, B1h, B1l, n, C_DIM);
        k_gemm7<0, 1, 256><<<dim3(gx), b256, 0, stream>>>(B1h, B1l, W3tH + wo, W3tL + wo,
            b3s + lyr * C_DIM, nullptr, B0h, B0l, n, C_DIM);
    }

    // final conv: agg -> C1(relu,256) -> C2(relu,64) -> C3(linear,256, fp32 out)
    k_agg2<1><<<gAgg, b256, 0, stream>>>(nullptr, B0h, B0l, off, adj, B1h, B1l, n);
    k_gemm7<1, 1, 256><<<dim3(gx), b256, 0, stream>>>(B1h, B1l, C1tH, C1tL, cb1,
        nullptr, B2h, B2l, n, C_DIM);
    k_gemm7<1, 1, 64><<<dim3(gx), b256, 0, stream>>>(B2h, B2l, C2tH, C2tL, cb2,
        nullptr, B1h, B1l, n, C_DIM);
    k_gemm7<0, 0, 256><<<dim3(gx), b256, 0, stream>>>(B1h, B1l, C3tH, C3tL, cb3,
        out, nullptr, nullptr, n, 64);
}

// Round 12
// 1194.523 us; speedup vs baseline: 1.1150x; 1.1150x over previous
//
#include <hip/hip_runtime.h>

constexpr int C_DIM = 256;

using f32x4  = __attribute__((ext_vector_type(4))) float;
using bf16x8 = __attribute__((ext_vector_type(8))) short;

__device__ __forceinline__ float uf(uint u) { return __uint_as_float(u); }
__device__ __forceinline__ uint  fu(float f) { return __float_as_uint(f); }

typedef __attribute__((address_space(3))) unsigned int lds_u32;
typedef const __attribute__((address_space(1))) unsigned int glb_u32;

// HBM -> LDS direct DMA, 16B per lane. lds dest = uniform base + lane*16.
__device__ __forceinline__ void gll16(const ushort* g, ushort* l) {
    __builtin_amdgcn_global_load_lds((glb_u32*)g, (lds_u32*)l, 16, 0, 0);
}

// ---------------- CSR build ----------------

__global__ void k_zero_i32(int* __restrict__ p, int n) {
    int i = blockIdx.x * blockDim.x + threadIdx.x;
    if (i < n) p[i] = 0;
}

__global__ void k_hist(const int* __restrict__ dst, int E, int* __restrict__ cnt) {
    int e = blockIdx.x * blockDim.x + threadIdx.x;
    if (e < E) atomicAdd(&cnt[dst[e]], 1);
}

__global__ __launch_bounds__(1024) void k_scan(const int* __restrict__ cnt,
                                               int* __restrict__ off, int n) {
    __shared__ int sh[1024];
    const int tid = threadIdx.x;
    const int chunk = (n + 1023) >> 10;
    const int s = tid * chunk;
    const int e = min(s + chunk, n);
    int sum = 0;
    for (int i = s; i < e; i++) sum += cnt[i];
    sh[tid] = sum;
    __syncthreads();
    for (int ofs = 1; ofs < 1024; ofs <<= 1) {
        int t = (tid >= ofs) ? sh[tid - ofs] : 0;
        __syncthreads();
        sh[tid] += t;
        __syncthreads();
    }
    int run = sh[tid] - sum;
    for (int i = s; i < e; i++) { off[i] = run; run += cnt[i]; }
    if (tid == 1023) off[n] = sh[1023];
}

__global__ void k_copy_i32(const int* __restrict__ a, int* __restrict__ b, int n) {
    int i = blockIdx.x * blockDim.x + threadIdx.x;
    if (i < n) b[i] = a[i];
}

__global__ void k_scatter(const int* __restrict__ src, const int* __restrict__ dst, int E,
                          int* __restrict__ cur, int* __restrict__ adj) {
    int e = blockIdx.x * blockDim.x + threadIdx.x;
    if (e < E) {
        int p = atomicAdd(&cur[dst[e]], 1);
        adj[p] = src[e];
    }
}

// ---------------- H = x + A*x, split-plane I/O, 4x-unrolled gather ----------------
// Latency-bound fix: issue 4 neighbor-row loads (8 vector loads) before any
// accumulation -> 4x memory-level parallelism per wave.
template <int SPLIT_IN>
__global__ __launch_bounds__(256) void k_agg3(const float* __restrict__ xf,
        const ushort* __restrict__ xh, const ushort* __restrict__ xl,
        const int* __restrict__ off, const int* __restrict__ adj,
        ushort* __restrict__ Hh, ushort* __restrict__ Hl, int n) {
    const int node = blockIdx.x * 4 + (threadIdx.x >> 6);
    if (node >= n) return;
    const int lane = threadIdx.x & 63;
    float a0, a1, a2, a3;
    if (SPLIT_IN) {
        const uint2 h  = ((const uint2*)(xh + (size_t)node * C_DIM))[lane];
        const uint2 lo = ((const uint2*)(xl + (size_t)node * C_DIM))[lane];
        a0 = uf(h.x << 16) + uf(lo.x << 16);
        a1 = uf(h.x & 0xffff0000u) + uf(lo.x & 0xffff0000u);
        a2 = uf(h.y << 16) + uf(lo.y << 16);
        a3 = uf(h.y & 0xffff0000u) + uf(lo.y & 0xffff0000u);
    } else {
        const float4 v = ((const float4*)(xf + (size_t)node * C_DIM))[lane];
        a0 = v.x; a1 = v.y; a2 = v.z; a3 = v.w;
    }
    const int s = off[node], e = off[node + 1];
    int j = s;
    for (; j + 4 <= e; j += 4) {
        const int s0 = adj[j], s1 = adj[j + 1], s2 = adj[j + 2], s3 = adj[j + 3];
        if (SPLIT_IN) {
            // issue all 8 loads before consuming any
            const uint2 h0 = ((const uint2*)(xh + (size_t)s0 * C_DIM))[lane];
            const uint2 l0 = ((const uint2*)(xl + (size_t)s0 * C_DIM))[lane];
            const uint2 h1 = ((const uint2*)(xh + (size_t)s1 * C_DIM))[lane];
            const uint2 l1 = ((const uint2*)(xl + (size_t)s1 * C_DIM))[lane];
            const uint2 h2 = ((const uint2*)(xh + (size_t)s2 * C_DIM))[lane];
            const uint2 l2 = ((const uint2*)(xl + (size_t)s2 * C_DIM))[lane];
            const uint2 h3 = ((const uint2*)(xh + (size_t)s3 * C_DIM))[lane];
            const uint2 l3 = ((const uint2*)(xl + (size_t)s3 * C_DIM))[lane];
            a0 += uf(h0.x << 16) + uf(l0.x << 16);
            a1 += uf(h0.x & 0xffff0000u) + uf(l0.x & 0xffff0000u);
            a2 += uf(h0.y << 16) + uf(l0.y << 16);
            a3 += uf(h0.y & 0xffff0000u) + uf(l0.y & 0xffff0000u);
            a0 += uf(h1.x << 16) + uf(l1.x << 16);
            a1 += uf(h1.x & 0xffff0000u) + uf(l1.x & 0xffff0000u);
            a2 += uf(h1.y << 16) + uf(l1.y << 16);
            a3 += uf(h1.y & 0xffff0000u) + uf(l1.y & 0xffff0000u);
            a0 += uf(h2.x << 16) + uf(l2.x << 16);
            a1 += uf(h2.x & 0xffff0000u) + uf(l2.x & 0xffff0000u);
            a2 += uf(h2.y << 16) + uf(l2.y << 16);
            a3 += uf(h2.y & 0xffff0000u) + uf(l2.y & 0xffff0000u);
            a0 += uf(h3.x << 16) + uf(l3.x << 16);
            a1 += uf(h3.x & 0xffff0000u) + uf(l3.x & 0xffff0000u);
            a2 += uf(h3.y << 16) + uf(l3.y << 16);
            a3 += uf(h3.y & 0xffff0000u) + uf(l3.y & 0xffff0000u);
        } else {
            const float4 v0 = ((const float4*)(xf + (size_t)s0 * C_DIM))[lane];
            const float4 v1 = ((const float4*)(xf + (size_t)s1 * C_DIM))[lane];
            const float4 v2 = ((const float4*)(xf + (size_t)s2 * C_DIM))[lane];
            const float4 v3 = ((const float4*)(xf + (size_t)s3 * C_DIM))[lane];
            a0 += v0.x; a1 += v0.y; a2 += v0.z; a3 += v0.w;
            a0 += v1.x; a1 += v1.y; a2 += v1.z; a3 += v1.w;
            a0 += v2.x; a1 += v2.y; a2 += v2.z; a3 += v2.w;
            a0 += v3.x; a1 += v3.y; a2 += v3.z; a3 += v3.w;
        }
    }
    for (; j < e; j++) {
        const int sn = adj[j];
        if (SPLIT_IN) {
            const uint2 h  = ((const uint2*)(xh + (size_t)sn * C_DIM))[lane];
            const uint2 lo = ((const uint2*)(xl + (size_t)sn * C_DIM))[lane];
            a0 += uf(h.x << 16) + uf(lo.x << 16);
            a1 += uf(h.x & 0xffff0000u) + uf(lo.x & 0xffff0000u);
            a2 += uf(h.y << 16) + uf(lo.y << 16);
            a3 += uf(h.y & 0xffff0000u) + uf(lo.y & 0xffff0000u);
        } else {
            const float4 v = ((const float4*)(xf + (size_t)sn * C_DIM))[lane];
            a0 += v.x; a1 += v.y; a2 += v.z; a3 += v.w;
        }
    }
    const uint u0 = fu(a0), u1 = fu(a1), u2 = fu(a2), u3 = fu(a3);
    uint2 ho, lo_;
    ho.x = (u0 >> 16) | (u1 & 0xffff0000u);
    ho.y = (u2 >> 16) | (u3 & 0xffff0000u);
    const float r0 = a0 - uf(u0 & 0xffff0000u);
    const float r1 = a1 - uf(u1 & 0xffff0000u);
    const float r2 = a2 - uf(u2 & 0xffff0000u);
    const float r3 = a3 - uf(u3 & 0xffff0000u);
    lo_.x = (fu(r0) >> 16) | (fu(r1) & 0xffff0000u);
    lo_.y = (fu(r2) >> 16) | (fu(r3) & 0xffff0000u);
    ((uint2*)(Hh + (size_t)node * C_DIM))[lane] = ho;
    ((uint2*)(Hl + (size_t)node * C_DIM))[lane] = lo_;
}

// ---------------- weight split + transpose ----------------
__global__ void k_split_w(const float* __restrict__ W, ushort* __restrict__ hi,
                          ushort* __restrict__ lo, int K, int M, int total) {
    int i = blockIdx.x * blockDim.x + threadIdx.x;
    if (i >= total) return;
    const int KM = K * M;
    const int mi = i / KM, rem = i - mi * KM;
    const int k = rem / M, m = rem - k * M;
    const float x = W[i];
    const uint u = fu(x);
    const float lf = x - uf(u & 0xffff0000u);
    const int oidx = mi * KM + m * K + k;
    hi[oidx] = (ushort)(u >> 16);
    lo[oidx] = (ushort)(fu(lf) >> 16);
}

// ---------------- Y = act(X @ W + b), pre-split bf16 MFMA, global_load_lds ----
// (R10 structure — measured best: 128x64 tile, XCD-chunk swizzle, LDS XOR swizzle)
template <int RELU, int OSPLIT, int CSHIFT>
__global__ __launch_bounds__(256) void k_gemm6(const ushort* __restrict__ Ah,
        const ushort* __restrict__ Al, const ushort* __restrict__ Bh,
        const ushort* __restrict__ Bl, const float* __restrict__ bias,
        float* __restrict__ Yf, ushort* __restrict__ Yh, ushort* __restrict__ Yl,
        int n, int K, int M, int q, int r) {
    // bijective XCD-chunk transform: round-robin dispatch -> contiguous chunks
    const int orig = blockIdx.x;
    const int xcd = orig & 7, idx = orig >> 3;
    const int base = xcd < r ? xcd * (q + 1) : r * (q + 1) + (xcd - r) * q;
    const int wg = base + idx;
    const int bx = wg >> CSHIFT, by = wg & ((1 << CSHIFT) - 1);
    const int row0 = bx * 128, col0 = by * 64;

    __shared__ ushort AsH[128 * 32], AsL[128 * 32], BsH[64 * 32], BsL[64 * 32];
    const int tid = threadIdx.x;
    const int l = tid & 63, w = tid >> 6;
    const int wr = w >> 1, wc = w & 1;
    const int lr = l & 15, lkq = l >> 4;
    f32x4 acc[4][2] = {};

    const int lsub = l >> 2;                               // row within 16-row chunk
    const int lkb  = (((l & 3) ^ ((l >> 3) & 3)) * 8);     // inverse-swizzled k-slot
    const int swz  = (lkq ^ ((lr >> 1) & 3)) * 8;          // read-side swizzle

    for (int k0 = 0; k0 < K; k0 += 32) {
        __syncthreads();   // previous iteration's LDS reads complete
        // 24 chunks of 1KB (A: 8/plane, B: 4/plane); 6 per wave, uniform branches
        for (int c = w; c < 24; c += 4) {
            if (c < 16) {
                const int a = c & 7;
                const int grow = min(row0 + a * 16 + lsub, n - 1);
                const ushort* gp = (c < 8 ? Ah : Al) + (size_t)grow * K + k0 + lkb;
                ushort* lp = (c < 8 ? AsH : AsL) + a * 512;
                gll16(gp, lp);
            } else {
                const int a = c & 3;
                const int col = col0 + a * 16 + lsub;
                const ushort* gp = (c < 20 ? Bh : Bl) + (size_t)col * K + k0 + lkb;
                ushort* lp = (c < 20 ? BsH : BsL) + a * 512;
                gll16(gp, lp);
            }
        }
        __syncthreads();   // vmcnt(0) drained before barrier: tile ready

        bf16x8 aH[4], aL[4], bH[2], bL[2];
#pragma unroll
        for (int f = 0; f < 4; f++) {
            const int rr = (wr * 64 + f * 16 + lr) * 32 + swz;
            aH[f] = *(const bf16x8*)&AsH[rr];
            aL[f] = *(const bf16x8*)&AsL[rr];
        }
#pragma unroll
        for (int f = 0; f < 2; f++) {
            const int rr = (wc * 32 + f * 16 + lr) * 32 + swz;
            bH[f] = *(const bf16x8*)&BsH[rr];
            bL[f] = *(const bf16x8*)&BsL[rr];
        }
#pragma unroll
        for (int fi = 0; fi < 4; fi++)
#pragma unroll
            for (int fj = 0; fj < 2; fj++) {
                acc[fi][fj] = __builtin_amdgcn_mfma_f32_16x16x32_bf16(aH[fi], bH[fj], acc[fi][fj], 0, 0, 0);
                acc[fi][fj] = __builtin_amdgcn_mfma_f32_16x16x32_bf16(aL[fi], bH[fj], acc[fi][fj], 0, 0, 0);
                acc[fi][fj] = __builtin_amdgcn_mfma_f32_16x16x32_bf16(aH[fi], bL[fj], acc[fi][fj], 0, 0, 0);
            }
    }

    // C/D layout: col = lane&15, row = (lane>>4)*4 + reg
#pragma unroll
    for (int fi = 0; fi < 4; fi++)
#pragma unroll
        for (int fj = 0; fj < 2; fj++) {
            const int col = col0 + wc * 32 + fj * 16 + lr;
            const float bv = bias[col];
#pragma unroll
            for (int rg = 0; rg < 4; rg++) {
                const int row = row0 + wr * 64 + fi * 16 + lkq * 4 + rg;
                if (row < n) {
                    float v = acc[fi][fj][rg] + bv;
                    if (RELU) v = fmaxf(v, 0.f);
                    const size_t oi = (size_t)row * M + col;
                    if (OSPLIT) {
                        const uint u = fu(v);
                        const float rv = v - uf(u & 0xffff0000u);
                        Yh[oi] = (ushort)(u >> 16);
                        Yl[oi] = (ushort)(fu(rv) >> 16);
                    } else {
                        Yf[oi] = v;
                    }
                }
            }
        }
}

// ---------------- driver ----------------

extern "C" void kernel_launch(void* const* d_in, const int* in_sizes, int n_in,
                              void* d_out, int out_size, void* d_ws, size_t ws_size,
                              hipStream_t stream) {
    const float* x   = (const float*)d_in[0];
    const int*   src = (const int*)d_in[1];
    const int*   dst = (const int*)d_in[2];
    const float* W1s = (const float*)d_in[3];
    const float* b1s = (const float*)d_in[4];
    const float* W2s = (const float*)d_in[5];
    const float* b2s = (const float*)d_in[6];
    const float* W3s = (const float*)d_in[7];
    const float* b3s = (const float*)d_in[8];
    const float* cW1 = (const float*)d_in[9];
    const float* cb1 = (const float*)d_in[10];
    const float* cW2 = (const float*)d_in[11];
    const float* cb2 = (const float*)d_in[12];
    const float* cW3 = (const float*)d_in[13];
    const float* cb3 = (const float*)d_in[14];

    const int n  = in_sizes[0] / C_DIM;                 // 50000
    const int E  = in_sizes[1];                         // 800000
    const int NL = in_sizes[3] / (C_DIM * C_DIM);       // 3 inner layers

    char* wsp = (char*)d_ws;
    size_t o = 0;
    auto take = [&](size_t bytes) -> char* {
        char* p = wsp + o;
        o = (o + bytes + 255) & ~(size_t)255;
        return p;
    };
    int* off = (int*)take(sizeof(int) * (size_t)(n + 1));
    int* cur = (int*)take(sizeof(int) * (size_t)n);
    int* adj = (int*)take(sizeof(int) * (size_t)E);
    const size_t plane = (size_t)n * C_DIM;
    ushort* B0h = (ushort*)take(2 * plane);
    ushort* B0l = (ushort*)take(2 * plane);
    ushort* B1h = (ushort*)take(2 * plane);
    ushort* B1l = (ushort*)take(2 * plane);
    // d_out doubles as the B2 ping-pong pair (dead before the final fp32 write)
    ushort* B2h = (ushort*)d_out;
    ushort* B2l = B2h + plane;

    const int szW  = NL * C_DIM * C_DIM;
    const int szC1 = C_DIM * C_DIM;
    const int szC2 = C_DIM * 64;
    const int szC3 = 64 * C_DIM;
    ushort* W1tH = (ushort*)take(2ull * szW);
    ushort* W1tL = (ushort*)take(2ull * szW);
    ushort* W2tH = (ushort*)take(2ull * szW);
    ushort* W2tL = (ushort*)take(2ull * szW);
    ushort* W3tH = (ushort*)take(2ull * szW);
    ushort* W3tL = (ushort*)take(2ull * szW);
    ushort* C1tH = (ushort*)take(2ull * szC1);
    ushort* C1tL = (ushort*)take(2ull * szC1);
    ushort* C2tH = (ushort*)take(2ull * szC2);
    ushort* C2tL = (ushort*)take(2ull * szC2);
    ushort* C3tH = (ushort*)take(2ull * szC3);
    ushort* C3tL = (ushort*)take(2ull * szC3);
    float* out = (float*)d_out;

    const dim3 b256(256);

    // weight preprocessing (split + transpose)
    k_split_w<<<dim3((szW + 255) / 256), b256, 0, stream>>>(W1s, W1tH, W1tL, C_DIM, C_DIM, szW);
    k_split_w<<<dim3((szW + 255) / 256), b256, 0, stream>>>(W2s, W2tH, W2tL, C_DIM, C_DIM, szW);
    k_split_w<<<dim3((szW + 255) / 256), b256, 0, stream>>>(W3s, W3tH, W3tL, C_DIM, C_DIM, szW);
    k_split_w<<<dim3((szC1 + 255) / 256), b256, 0, stream>>>(cW1, C1tH, C1tL, C_DIM, C_DIM, szC1);
    k_split_w<<<dim3((szC2 + 255) / 256), b256, 0, stream>>>(cW2, C2tH, C2tL, C_DIM, 64, szC2);
    k_split_w<<<dim3((szC3 + 255) / 256), b256, 0, stream>>>(cW3, C3tH, C3tL, 64, C_DIM, szC3);

    // CSR build
    k_zero_i32<<<dim3((n + 255) / 256), b256, 0, stream>>>(cur, n);
    k_hist<<<dim3((E + 255) / 256), b256, 0, stream>>>(dst, E, cur);
    k_scan<<<1, 1024, 0, stream>>>(cur, off, n);
    k_copy_i32<<<dim3((n + 255) / 256), b256, 0, stream>>>(off, cur, n);
    k_scatter<<<dim3((E + 255) / 256), b256, 0, stream>>>(src, dst, E, cur, adj);

    const int gx = (n + 127) / 128;          // 391 row panels
    const dim3 gAgg((n + 3) / 4);

    const int nwg4 = gx * 4, q4 = nwg4 / 8, r4 = nwg4 % 8;  // full-width GEMMs
    const int nwg1 = gx,     q1 = nwg1 / 8, r1 = nwg1 % 8;  // M=64 GEMM

    // inner GIN layers: agg -> G1(relu) -> G2(relu) -> G3(linear)
    for (int lyr = 0; lyr < NL; lyr++) {
        const size_t wo = (size_t)lyr * C_DIM * C_DIM;
        if (lyr == 0)
            k_agg3<0><<<gAgg, b256, 0, stream>>>(x, nullptr, nullptr, off, adj, B1h, B1l, n);
        else
            k_agg3<1><<<gAgg, b256, 0, stream>>>(nullptr, B0h, B0l, off, adj, B1h, B1l, n);
        k_gemm6<1, 1, 2><<<dim3(nwg4), b256, 0, stream>>>(B1h, B1l, W1tH + wo, W1tL + wo,
            b1s + lyr * C_DIM, nullptr, B2h, B2l, n, C_DIM, C_DIM, q4, r4);
        k_gemm6<1, 1, 2><<<dim3(nwg4), b256, 0, stream>>>(B2h, B2l, W2tH + wo, W2tL + wo,
            b2s + lyr * C_DIM, nullptr, B1h, B1l, n, C_DIM, C_DIM, q4, r4);
        k_gemm6<0, 1, 2><<<dim3(nwg4), b256, 0, stream>>>(B1h, B1l, W3tH + wo, W3tL + wo,
            b3s + lyr * C_DIM, nullptr, B0h, B0l, n, C_DIM, C_DIM, q4, r4);
    }

    // final conv: agg -> C1(relu,256) -> C2(relu,64) -> C3(linear,256, fp32 out)
    k_agg3<1><<<gAgg, b256, 0, stream>>>(nullptr, B0h, B0l, off, adj, B1h, B1l, n);
    k_gemm6<1, 1, 2><<<dim3(nwg4), b256, 0, stream>>>(B1h, B1l, C1tH, C1tL, cb1,
        nullptr, B2h, B2l, n, C_DIM, C_DIM, q4, r4);
    k_gemm6<1, 1, 0><<<dim3(nwg1), b256, 0, stream>>>(B2h, B2l, C2tH, C2tL, cb2,
        nullptr, B1h, B1l, n, C_DIM, 64, q1, r1);
    k_gemm6<0, 0, 2><<<dim3(nwg4), b256, 0, stream>>>(B1h, B1l, C3tH, C3tL, cb3,
        out, nullptr, nullptr, n, 64, C_DIM, q4, r4);
}